// Round 18
// baseline (787.372 us; speedup 1.0000x reference)
//
#include <hip/hip_runtime.h>
#include <math.h>

#define EMB 128
#define MID 192
#define SEQ 128
#define BATCH 16
#define NPAIR 127
#define KCLS 5
#define EPSF 1e-5f

// ws float-offsets
// WYT interleaved granules: logical slice s in [0,512) holds 64 floats j;
//   physical float4 index = (j>>2)*512 + s  (lane-consecutive => coalesced).
//   Wy[k][o]: q=k>>6, j=k&63, s=o*4+q.  k_seq thread t uses slice t (o=t>>2,q=t&3).
// WXXT interleaved: Wxx[k][c]: hh=k>>6, j=k&63, s=c*2+hh. k_seq slice t (c=t>>1,hh=t&1).
#define OFF_WYT   0                      // 512*64 = 32768
#define OFF_BY    32768                  // 128
#define OFF_WXXT  32896                  // 512*64 = 32768
#define OFF_BXX   65664                  // 256
#define OFF_NODES 65920                  // B*128*128 = 262144
#define OFF_YC    328064                 // B*127*128 = 260096
#define OFF_L0    588160                 // B*127

// ---------------- composite weights (interleaved for coalesced slices) -----
__global__ void k_comp(const float* __restrict__ W1, const float* __restrict__ b1,
                       const float* __restrict__ W2, const float* __restrict__ b2,
                       const float* __restrict__ W3, const float* __restrict__ b3,
                       const float* __restrict__ W4, const float* __restrict__ b4,
                       float* __restrict__ ws) {
    int tid = blockIdx.x * blockDim.x + threadIdx.x;
    if (tid < 32768) {                    // Wy[k][o], k<256, o<128
        int k = tid >> 7, o = tid & 127;
        float a = 0.f;
        for (int j = 0; j < MID; ++j) a += W1[k*MID+j] * W2[j*EMB+o];
        int q = k >> 6, jj = k & 63;
        int s = o*4 + q;
        ws[OFF_WYT + (size_t)(jj >> 2)*2048 + s*4 + (jj & 3)] = a;
    } else if (tid < 65536) {             // Wxx[k][c], k<128, c<256
        int t = tid - 32768;
        int k = t >> 8, c = t & 255;
        float a = 0.f;
        for (int j = 0; j < MID; ++j) a += W3[k*MID+j] * W4[j*256+c];
        int hh = k >> 6, jj = k & 63;
        int s = c*2 + hh;
        ws[OFF_WXXT + (size_t)(jj >> 2)*2048 + s*4 + (jj & 3)] = a;
    } else if (tid < 65536 + 128) {       // by
        int o = tid - 65536;
        float a = b2[o];
        for (int j = 0; j < MID; ++j) a += b1[j] * W2[j*EMB+o];
        ws[OFF_BY + o] = a;
    } else if (tid < 65536 + 128 + 256) { // bxx
        int o = tid - 65536 - 128;
        float a = b4[o];
        for (int j = 0; j < MID; ++j) a += b3[j] * W4[j*256+o];
        ws[OFF_BXX + o] = a;
    }
}

// ---------------- gather embeddings ----------------
__global__ void k_nodes(const int* __restrict__ inp, const float* __restrict__ emb,
                        float* __restrict__ ws) {
    int tid = blockIdx.x * blockDim.x + threadIdx.x;  // B*128*128
    if (tid >= BATCH*SEQ*EMB) return;
    int d = tid & 127;
    int bs = tid >> 7;
    int tok = inp[bs];
    ws[OFF_NODES + tid] = emb[tok*EMB + d];
}

// DPP cross-lane helpers (VALU-speed).
#define DPPF(x, ctrl) __int_as_float(__builtin_amdgcn_update_dpp(0, __float_as_int(x), (ctrl), 0xF, 0xF, true))
#define DPPI(x, ctrl) __builtin_amdgcn_update_dpp(0, (x), (ctrl), 0xF, 0xF, true)
#define SWZ16F(x) __int_as_float(__builtin_amdgcn_ds_swizzle(__float_as_int(x), 0x401F))
#define SWZ16I(x) __builtin_amdgcn_ds_swizzle((x), 0x401F)

// ---------------- initial 127 pair losses: 8 groups x 16 rows ---------------
__global__ void __launch_bounds__(512, 1) k_init(float* __restrict__ ws) {
    __shared__ float s_x[2][2*EMB];
    __shared__ float s_red[4][2][EMB];
    __shared__ float s_redx[2][2][256];
    __shared__ float s_y[2][EMB];
    __shared__ float s_by[EMB];
    __shared__ float s_bxx[2*EMB];
    __shared__ float s_ls[2][2];
    int tid = threadIdx.x;
    int b = blockIdx.x >> 3, g = blockIdx.x & 7;
    float wy[64], wxx[64];
    {
        int sA = (tid & 127)*4 + (tid >> 7);
        const float4* gw = (const float4*)(ws + OFF_WYT);
        #pragma unroll
        for (int i = 0; i < 16; ++i) { float4 v = gw[i*512 + sA]; wy[4*i]=v.x; wy[4*i+1]=v.y; wy[4*i+2]=v.z; wy[4*i+3]=v.w; }
        int sB = (tid & 255)*2 + (tid >> 8);
        const float4* gx = (const float4*)(ws + OFF_WXXT);
        #pragma unroll
        for (int i = 0; i < 16; ++i) { float4 v = gx[i*512 + sB]; wxx[4*i]=v.x; wxx[4*i+1]=v.y; wxx[4*i+2]=v.z; wxx[4*i+3]=v.w; }
    }
    if (tid < EMB) s_by[tid] = ws[OFF_BY + tid];
    if (tid < 2*EMB) s_bxx[tid] = ws[OFF_BXX + tid];
    const float* nodes = ws + OFF_NODES + (size_t)b*SEQ*EMB;
    float* yc = ws + OFF_YC + (size_t)b*NPAIR*EMB;
    int q4 = tid >> 7, o = tid & 127;
    int hh = tid >> 8, c = tid & 255;
    int p_s = tid >> 8, kk = tid & 255;
    __syncthreads();
    for (int i = 0; i < 8; ++i) {
        int base = g*16 + i*2;
        {
            int j = base + p_s;
            int jj = j < NPAIR ? j : NPAIR - 1;
            s_x[p_s][kk] = nodes[(jj + (kk < 128 ? 1 : 0))*EMB + (kk & 127)];
        }
        __syncthreads();
        float a0 = 0.f, a1 = 0.f;
        #pragma unroll
        for (int j = 0; j < 64; ++j) {
            float w = wy[j];
            a0 += s_x[0][q4*64 + j] * w;
            a1 += s_x[1][q4*64 + j] * w;
        }
        s_red[q4][0][o] = a0;
        s_red[q4][1][o] = a1;
        __syncthreads();
        if (tid < 256) {
            int p = tid >> 7, oo = tid & 127;
            float yv = s_red[0][p][oo] + s_red[1][p][oo] + s_red[2][p][oo] + s_red[3][p][oo] + s_by[oo];
            s_y[p][oo] = yv;
            int j2 = base + p;
            if (j2 < NPAIR) yc[(size_t)j2*EMB + oo] = yv;
        }
        __syncthreads();
        float c0 = 0.f, c1 = 0.f;
        #pragma unroll
        for (int j = 0; j < 64; ++j) {
            float w = wxx[j];
            c0 += s_y[0][hh*64 + j] * w;
            c1 += s_y[1][hh*64 + j] * w;
        }
        s_redx[hh][0][c] = c0;
        s_redx[hh][1][c] = c1;
        __syncthreads();
        if (tid < 256) {   // waves 0-3: (pair p2, half h2)
            int w = tid >> 6, lane = tid & 63;
            int p2 = w >> 1, h2 = w & 1;
            int cA = h2*128 + lane, cB = cA + 64;
            float v0 = s_redx[0][p2][cA] + s_redx[1][p2][cA] + s_bxx[cA];
            float v1 = s_redx[0][p2][cB] + s_redx[1][p2][cB] + s_bxx[cB];
            float m = fmaxf(v0, v1);
            for (int s = 32; s; s >>= 1) m = fmaxf(m, __shfl_xor(m, s, 64));
            float se = expf(v0 - m) + expf(v1 - m);
            for (int s = 32; s; s >>= 1) se += __shfl_xor(se, s, 64);
            float lse = m + logf(se);
            float o0 = s_x[p2][cA], o1 = s_x[p2][cB];
            float term = o0*(v0 - lse) + o1*(v1 - lse);
            for (int s = 32; s; s >>= 1) term += __shfl_xor(term, s, 64);
            if (lane == 0) s_ls[p2][h2] = -term;
        }
        __syncthreads();
        if (tid < 2) {
            int j2 = base + tid;
            if (j2 < NPAIR) {
                float l = ((1.f+EPSF)*s_ls[tid][0] + (1.f+EPSF)*s_ls[tid][1]) / (2.f + EPSF);
                ws[OFF_L0 + b*NPAIR + j2] = l;
            }
        }
        __syncthreads();
    }
}

// padded staged-x access: 64-chunk stride 72 floats
#define SX(p, c) s_x[p][(((c) >> 6)*72) + ((c) & 63)]

#define S2G(P, i4) \
    c0 = fmaf(y0p[(i4)+0], P.x, c0); c1 = fmaf(y1p[(i4)+0], P.x, c1); \
    c0 = fmaf(y0p[(i4)+1], P.y, c0); c1 = fmaf(y1p[(i4)+1], P.y, c1); \
    c0 = fmaf(y0p[(i4)+2], P.z, c0); c1 = fmaf(y1p[(i4)+2], P.z, c1); \
    c0 = fmaf(y0p[(i4)+3], P.w, c0); c1 = fmaf(y1p[(i4)+3], P.w, c1);

// ---------------- sequential scan: one block (512 thr) per batch row --------
// R16 base (best verified: 380us k_seq). wxx prefetch reinstated WITHOUT the
// sched_barrier (R17's fence serialized S1's wy stream) and with the hh*64
// y-half offset fixed (R17's correctness bug). If the scheduler keeps the
// issue order, the wxx latency hides under S1; if it sinks them, behavior
// degenerates to R16 exactly. 4 barriers/step: S1 | S2 | softmax||argmin | S4.
__global__ void __launch_bounds__(512, 1) k_seq(float* __restrict__ ws,
                      const float* __restrict__ Wk, const float* __restrict__ bkv,
                      float* __restrict__ out) {
    __shared__ float s_nodes[SEQ*EMB];    // 64 KB
    __shared__ float s_yc[NPAIR*EMB];     // 63.5 KB
    __shared__ float s_x[2][4*72];        // padded chunks
    __shared__ float s_y[2][EMB];
    __shared__ float s_xx[2][2*EMB];
    __shared__ float s_by[EMB];
    __shared__ float s_bxx[2*EMB];
    __shared__ float s_ls[2][2];
    __shared__ float s_loss[2][SEQ];      // ping-pong
    __shared__ float s_cnt[2][SEQ];
    __shared__ int   s_nslot[2][SEQ];
    __shared__ int   s_yslot[2][SEQ];
    __shared__ float s_restv[4];
    __shared__ int   s_resti[4];
    __shared__ float s_log[KCLS];

    int tid = threadIdx.x;
    int b = blockIdx.x;
    const float4* gwy  = (const float4*)(ws + OFF_WYT);   // slice == tid
    const float4* gwxx = (const float4*)(ws + OFF_WXXT);  // slice == tid
    {
        const float4* gn = (const float4*)(ws + OFF_NODES + (size_t)b*SEQ*EMB);
        float4* sn = (float4*)s_nodes;
        for (int i = tid; i < SEQ*EMB/4; i += 512) sn[i] = gn[i];
        const float4* gy = (const float4*)(ws + OFF_YC + (size_t)b*NPAIR*EMB);
        float4* sy = (float4*)s_yc;
        for (int i = tid; i < NPAIR*EMB/4; i += 512) sy[i] = gy[i];
    }
    if (tid < EMB) s_by[tid] = ws[OFF_BY + tid];
    if (tid < 2*EMB) s_bxx[tid] = ws[OFF_BXX + tid];
    if (tid < NPAIR) { s_loss[0][tid] = ws[OFF_L0 + b*NPAIR + tid]; s_yslot[0][tid] = tid; }
    if (tid < SEQ)   { s_cnt[0][tid] = 1.f; s_nslot[0][tid] = tid; }

    float acc = 0.f;
    int cur = 0;
    int q0c = -1, q1c = -1;               // current-step recompute positions (uniform regs)
    const int q4 = tid & 3,  oy = tid >> 2;   // S1 roles: k-chunk in lane&3
    const int hh = tid & 1,  cx = tid >> 1;   // S2 roles: k-half in lane&1
    const int sp = tid >> 8, skk = tid & 255; // stage roles
    __syncthreads();

    #pragma unroll 1
    for (int t = 0; t < NPAIR; ++t) {
        const int L = SEQ - t;
        if (t > 0) {
            // ---- prefetch wxx (issued before S1; consumed in S2)
            float4 P0  = gwxx[0*512+tid],  P1  = gwxx[1*512+tid];
            float4 P2  = gwxx[2*512+tid],  P3  = gwxx[3*512+tid];
            float4 P4  = gwxx[4*512+tid],  P5  = gwxx[5*512+tid];
            float4 P6  = gwxx[6*512+tid],  P7  = gwxx[7*512+tid];
            float4 P8  = gwxx[8*512+tid],  P9  = gwxx[9*512+tid];
            float4 P10 = gwxx[10*512+tid], P11 = gwxx[11*512+tid];
            float4 P12 = gwxx[12*512+tid], P13 = gwxx[13*512+tid];
            float4 P14 = gwxx[14*512+tid], P15 = gwxx[15*512+tid];
            // ---- S1: y = x @ Wy + by; wy streamed inline (coalesced);
            //          x via ds_read_b128; DPP-reduce 4 chunks
            {
                const float4* x0q = (const float4*)(&s_x[0][q4*72]);
                const float4* x1q = (const float4*)(&s_x[1][q4*72]);
                float a0 = 0.f, a1 = 0.f;
                #pragma unroll
                for (int i = 0; i < 16; ++i) {
                    float4 w  = gwy[i*512 + tid];
                    float4 u0 = x0q[i];
                    float4 u1 = x1q[i];
                    a0 = fmaf(u0.x, w.x, a0); a1 = fmaf(u1.x, w.x, a1);
                    a0 = fmaf(u0.y, w.y, a0); a1 = fmaf(u1.y, w.y, a1);
                    a0 = fmaf(u0.z, w.z, a0); a1 = fmaf(u1.z, w.z, a1);
                    a0 = fmaf(u0.w, w.w, a0); a1 = fmaf(u1.w, w.w, a1);
                }
                a0 += DPPF(a0, 0xB1); a1 += DPPF(a1, 0xB1);
                a0 += DPPF(a0, 0x4E); a1 += DPPF(a1, 0x4E);
                if (q4 == 0) {
                    float bb = s_by[oy];
                    float y0 = a0 + bb, y1 = a1 + bb;
                    s_y[0][oy] = y0; s_y[1][oy] = y1;
                    s_yc[(size_t)s_yslot[cur][q0c]*EMB + oy] = y0;
                    s_yc[(size_t)s_yslot[cur][q1c]*EMB + oy] = y1;
                }
            }
            __syncthreads();
            // ---- S2: xx = y @ Wxx + bxx; Wxx from prefetched regs;
            //          y-half hh*64 (bugfix vs R17)
            {
                const float* y0p = &s_y[0][hh*64];
                const float* y1p = &s_y[1][hh*64];
                float c0 = 0.f, c1 = 0.f;
                S2G(P0, 0)   S2G(P1, 4)   S2G(P2, 8)   S2G(P3, 12)
                S2G(P4, 16)  S2G(P5, 20)  S2G(P6, 24)  S2G(P7, 28)
                S2G(P8, 32)  S2G(P9, 36)  S2G(P10, 40) S2G(P11, 44)
                S2G(P12, 48) S2G(P13, 52) S2G(P14, 56) S2G(P15, 60)
                c0 += DPPF(c0, 0xB1); c1 += DPPF(c1, 0xB1);
                if (hh == 0) {
                    float bb = s_bxx[cx];
                    s_xx[0][cx] = c0 + bb;
                    s_xx[1][cx] = c1 + bb;
                }
            }
            __syncthreads();
        }
        // ---- S3: softmax losses (waves 0-1, DPP trees) || argmin (waves 2-3)
        if (t > 0 && tid < 128) {
            int p2 = tid >> 6, h2 = (tid >> 5) & 1, l5 = tid & 31;
            int base = h2*128 + l5;
            float v0 = s_xx[p2][base],      v1 = s_xx[p2][base+32];
            float v2 = s_xx[p2][base+64],   v3 = s_xx[p2][base+96];
            float o0 = SX(p2, base),        o1v = SX(p2, base+32);
            float o2 = SX(p2, base+64),     o3 = SX(p2, base+96);
            float m   = fmaxf(fmaxf(v0, v1), fmaxf(v2, v3));
            float sov = v0*o0 + v1*o1v + v2*o2 + v3*o3;
            float so  = (o0 + o1v) + (o2 + o3);
            m = fmaxf(m, DPPF(m, 0xB1));  sov += DPPF(sov, 0xB1);  so += DPPF(so, 0xB1);
            m = fmaxf(m, DPPF(m, 0x4E));  sov += DPPF(sov, 0x4E);  so += DPPF(so, 0x4E);
            m = fmaxf(m, DPPF(m, 0x124)); sov += DPPF(sov, 0x124); so += DPPF(so, 0x124);
            m = fmaxf(m, DPPF(m, 0x128)); sov += DPPF(sov, 0x128); so += DPPF(so, 0x128);
            m = fmaxf(m, SWZ16F(m));      sov += SWZ16F(sov);      so += SWZ16F(so);
            float se = expf(v0 - m) + expf(v1 - m) + expf(v2 - m) + expf(v3 - m);
            se += DPPF(se, 0xB1);
            se += DPPF(se, 0x4E);
            se += DPPF(se, 0x124);
            se += DPPF(se, 0x128);
            se += SWZ16F(se);
            if (l5 == 0) s_ls[p2][h2] = (m + logf(se))*so - sov;   // = -sum o*(v-lse)
        } else if (tid >= 128 && tid < 256) {
            int j = tid - 128;
            float v = (j <= L-2 && j != q0c && j != q1c) ? s_loss[cur][j] : INFINITY;
            int ii = j;
            {   float ov = DPPF(v, 0xB1);  int oi = DPPI(ii, 0xB1);
                bool tk = (ov < v) || (ov == v && oi < ii); v = tk ? ov : v; ii = tk ? oi : ii; }
            {   float ov = DPPF(v, 0x4E);  int oi = DPPI(ii, 0x4E);
                bool tk = (ov < v) || (ov == v && oi < ii); v = tk ? ov : v; ii = tk ? oi : ii; }
            {   float ov = DPPF(v, 0x124); int oi = DPPI(ii, 0x124);
                bool tk = (ov < v) || (ov == v && oi < ii); v = tk ? ov : v; ii = tk ? oi : ii; }
            {   float ov = DPPF(v, 0x128); int oi = DPPI(ii, 0x128);
                bool tk = (ov < v) || (ov == v && oi < ii); v = tk ? ov : v; ii = tk ? oi : ii; }
            {   float ov = SWZ16F(v);      int oi = SWZ16I(ii);
                bool tk = (ov < v) || (ov == v && oi < ii); v = tk ? ov : v; ii = tk ? oi : ii; }
            if ((j & 31) == 0) { s_restv[j >> 5] = v; s_resti[j >> 5] = ii; }
        }
        __syncthreads();
        // ---- S4: uniform combine + ping-pong shift + father write + stage
        float l0 = INFINITY, l1 = INFINITY;
        if (t > 0) {
            float n1a = s_cnt[cur][q0c+1], n2a = s_cnt[cur][q0c];
            l0 = ((n1a + EPSF)*s_ls[0][0] + (n2a + EPSF)*s_ls[0][1]) / (n1a + n2a + EPSF);
            float n1b = s_cnt[cur][q1c+1], n2b = s_cnt[cur][q1c];
            l1 = ((n1b + EPSF)*s_ls[1][0] + (n2b + EPSF)*s_ls[1][1]) / (n1b + n2b + EPSF);
        }
        float bv = s_restv[0]; int bi = s_resti[0];
        #pragma unroll
        for (int g = 1; g < 4; ++g) {
            float rv = s_restv[g]; int ri = s_resti[g];
            if (rv < bv || (rv == bv && ri < bi)) { bv = rv; bi = ri; }
        }
        if (t > 0) {   // q1 first then q0, so q0 wins ties (first-index rule)
            if (l1 < bv || (l1 == bv && q1c < bi)) { bv = l1; bi = q1c; }
            if (l0 < bv || (l0 == bv && q0c < bi)) { bv = l0; bi = q0c; }
        }
        if (tid == 0) acc += bv;
        const int idx = bi;
        const int pos = idx > 0 ? idx - 1 : 0;
        const bool dS = idx > 0;
        const float fcnt = s_cnt[cur][idx] + s_cnt[cur][idx == 0 ? L-1 : idx-1];
        const int slotFr = s_nslot[cur][pos];
        const int ysIr   = s_yslot[cur][idx];
        const int nxt = cur ^ 1;
        if (tid < NPAIR) {
            int sh = (dS && tid >= pos+1 && tid <= L-3) ? 1 : 0;
            int sj = tid + sh;
            float v = (sj == q0c) ? l0 : (sj == q1c) ? l1 : s_loss[cur][sj];
            s_loss[nxt][tid]  = v;
            s_yslot[nxt][tid] = s_yslot[cur][sj];
        }
        if (tid < SEQ) {
            int sh = (dS && tid >= pos+1 && tid <= L-2) ? 1 : 0;
            s_cnt[nxt][tid]   = (tid == pos) ? fcnt : s_cnt[cur][tid + sh];
            s_nslot[nxt][tid] = s_nslot[cur][tid + sh];
        }
        // next-step roles (uniform)
        q0c = pos >= 1 ? pos - 1 : 0;
        q1c = pos;
        // father write + next-step x staging (race-free: stage's father
        // position redirects to s_yc; other slots differ from slotFr)
        if (tid < EMB) s_nodes[slotFr*EMB + tid] = s_yc[(size_t)ysIr*EMB + tid];
        {
            int qq = (sp ? q1c : q0c) + (skk < 128 ? 1 : 0);
            bool sYc = (qq == q1c);   // father position reads fresh y from yc
            int sh = (dS && qq >= pos+1 && qq <= L-2) ? 1 : 0;
            int ms = s_nslot[cur][qq + sh];
            float xv = sYc ? s_yc[(size_t)ysIr*EMB + (skk & 127)]
                           : s_nodes[(size_t)ms*EMB + (skk & 127)];
            s_x[sp][((skk >> 6)*72) + (skk & 63)] = xv;
        }
        cur = nxt;
        __syncthreads();
    }
    // ---- prediction from root = s_nodes[s_nslot[cur][0]]
    {
        int w = tid >> 6, l = tid & 63;
        if (w < KCLS) {
            const float* root = s_nodes + (size_t)s_nslot[cur][0]*EMB;
            float p = root[2*l]*Wk[(2*l)*KCLS + w] + root[2*l+1]*Wk[(2*l+1)*KCLS + w];
            for (int s = 32; s; s >>= 1) p += __shfl_xor(p, s, 64);
            if (l == 0) s_log[w] = p + bkv[w];
        }
    }
    __syncthreads();
    if (tid == 0) {
        int best = 0;
        for (int cc = 1; cc < KCLS; ++cc) if (s_log[cc] > s_log[best]) best = cc;
        out[b] = (float)best;
        atomicAdd(&out[BATCH], acc * (1.f/16.f));
    }
}

extern "C" void kernel_launch(void* const* d_in, const int* in_sizes, int n_in,
                              void* d_out, int out_size, void* d_ws, size_t ws_size,
                              hipStream_t stream) {
    const int*   inp = (const int*)d_in[0];
    const float* emb = (const float*)d_in[1];
    const float* W1  = (const float*)d_in[2];
    const float* b1  = (const float*)d_in[3];
    const float* W2  = (const float*)d_in[4];
    const float* b2  = (const float*)d_in[5];
    const float* W3  = (const float*)d_in[6];
    const float* b3  = (const float*)d_in[7];
    const float* W4  = (const float*)d_in[8];
    const float* b4  = (const float*)d_in[9];
    const float* Wk  = (const float*)d_in[10];
    const float* bk  = (const float*)d_in[11];
    float* out = (float*)d_out;
    float* ws  = (float*)d_ws;

    hipMemsetAsync(d_out, 0, (size_t)out_size * sizeof(float), stream);

    k_comp<<<(65920 + 255) / 256, 256, 0, stream>>>(W1, b1, W2, b2, W3, b3, W4, b4, ws);
    k_nodes<<<(BATCH*SEQ*EMB + 255) / 256, 256, 0, stream>>>(inp, emb, ws);
    k_init<<<BATCH * 8, 512, 0, stream>>>(ws);
    k_seq<<<BATCH, 512, 0, stream>>>(ws, Wk, bk, out);
}

// Round 19
// 490.963 us; speedup vs baseline: 1.6037x; 1.6037x over previous
//
#include <hip/hip_runtime.h>
#include <math.h>

#define EMB 128
#define MID 192
#define SEQ 128
#define BATCH 16
#define NPAIR 127
#define KCLS 5
#define EPSF 1e-5f

// ws float-offsets
// WYT interleaved granules: logical slice s in [0,512) holds 64 floats j;
//   physical float4 index = (j>>2)*512 + s  (lane-consecutive => coalesced).
//   Wy[k][o]: q=k>>6, j=k&63, s=o*4+q.  k_seq thread t uses slice t (o=t>>2,q=t&3).
// WXXT interleaved: Wxx[k][c]: hh=k>>6, j=k&63, s=c*2+hh. k_seq slice t (c=t>>1,hh=t&1).
#define OFF_WYT   0                      // 512*64 = 32768
#define OFF_BY    32768                  // 128
#define OFF_WXXT  32896                  // 512*64 = 32768
#define OFF_BXX   65664                  // 256
#define OFF_NODES 65920                  // B*128*128 = 262144
#define OFF_YC    328064                 // B*127*128 = 260096
#define OFF_L0    588160                 // B*127

// ---------------- composite weights (interleaved for coalesced slices) -----
__global__ void k_comp(const float* __restrict__ W1, const float* __restrict__ b1,
                       const float* __restrict__ W2, const float* __restrict__ b2,
                       const float* __restrict__ W3, const float* __restrict__ b3,
                       const float* __restrict__ W4, const float* __restrict__ b4,
                       float* __restrict__ ws) {
    int tid = blockIdx.x * blockDim.x + threadIdx.x;
    if (tid < 32768) {                    // Wy[k][o], k<256, o<128
        int k = tid >> 7, o = tid & 127;
        float a = 0.f;
        for (int j = 0; j < MID; ++j) a += W1[k*MID+j] * W2[j*EMB+o];
        int q = k >> 6, jj = k & 63;
        int s = o*4 + q;
        ws[OFF_WYT + (size_t)(jj >> 2)*2048 + s*4 + (jj & 3)] = a;
    } else if (tid < 65536) {             // Wxx[k][c], k<128, c<256
        int t = tid - 32768;
        int k = t >> 8, c = t & 255;
        float a = 0.f;
        for (int j = 0; j < MID; ++j) a += W3[k*MID+j] * W4[j*256+c];
        int hh = k >> 6, jj = k & 63;
        int s = c*2 + hh;
        ws[OFF_WXXT + (size_t)(jj >> 2)*2048 + s*4 + (jj & 3)] = a;
    } else if (tid < 65536 + 128) {       // by
        int o = tid - 65536;
        float a = b2[o];
        for (int j = 0; j < MID; ++j) a += b1[j] * W2[j*EMB+o];
        ws[OFF_BY + o] = a;
    } else if (tid < 65536 + 128 + 256) { // bxx
        int o = tid - 65536 - 128;
        float a = b4[o];
        for (int j = 0; j < MID; ++j) a += b3[j] * W4[j*256+o];
        ws[OFF_BXX + o] = a;
    }
}

// ---------------- gather embeddings ----------------
__global__ void k_nodes(const int* __restrict__ inp, const float* __restrict__ emb,
                        float* __restrict__ ws) {
    int tid = blockIdx.x * blockDim.x + threadIdx.x;  // B*128*128
    if (tid >= BATCH*SEQ*EMB) return;
    int d = tid & 127;
    int bs = tid >> 7;
    int tok = inp[bs];
    ws[OFF_NODES + tid] = emb[tok*EMB + d];
}

// DPP cross-lane helpers (VALU-speed).
// quad_perm xor1 = 0xB1, xor2 = 0x4E; row_ror:4 = 0x124, row_ror:8 = 0x128.
#define DPPF(x, ctrl) __int_as_float(__builtin_amdgcn_update_dpp(0, __float_as_int(x), (ctrl), 0xF, 0xF, true))
#define DPPI(x, ctrl) __builtin_amdgcn_update_dpp(0, (x), (ctrl), 0xF, 0xF, true)
#define SWZ16F(x) __int_as_float(__builtin_amdgcn_ds_swizzle(__float_as_int(x), 0x401F))
#define SWZ16I(x) __builtin_amdgcn_ds_swizzle((x), 0x401F)

// ---------------- initial 127 pair losses: 8 groups x 16 rows ---------------
__global__ void __launch_bounds__(512, 1) k_init(float* __restrict__ ws) {
    __shared__ float s_x[2][2*EMB];
    __shared__ float s_red[4][2][EMB];
    __shared__ float s_redx[2][2][256];
    __shared__ float s_y[2][EMB];
    __shared__ float s_by[EMB];
    __shared__ float s_bxx[2*EMB];
    __shared__ float s_ls[2][2];
    int tid = threadIdx.x;
    int b = blockIdx.x >> 3, g = blockIdx.x & 7;
    float wy[64], wxx[64];
    {
        int sA = (tid & 127)*4 + (tid >> 7);
        const float4* gw = (const float4*)(ws + OFF_WYT);
        #pragma unroll
        for (int i = 0; i < 16; ++i) { float4 v = gw[i*512 + sA]; wy[4*i]=v.x; wy[4*i+1]=v.y; wy[4*i+2]=v.z; wy[4*i+3]=v.w; }
        int sB = (tid & 255)*2 + (tid >> 8);
        const float4* gx = (const float4*)(ws + OFF_WXXT);
        #pragma unroll
        for (int i = 0; i < 16; ++i) { float4 v = gx[i*512 + sB]; wxx[4*i]=v.x; wxx[4*i+1]=v.y; wxx[4*i+2]=v.z; wxx[4*i+3]=v.w; }
    }
    if (tid < EMB) s_by[tid] = ws[OFF_BY + tid];
    if (tid < 2*EMB) s_bxx[tid] = ws[OFF_BXX + tid];
    const float* nodes = ws + OFF_NODES + (size_t)b*SEQ*EMB;
    float* yc = ws + OFF_YC + (size_t)b*NPAIR*EMB;
    int q4 = tid >> 7, o = tid & 127;
    int hh = tid >> 8, c = tid & 255;
    int p_s = tid >> 8, kk = tid & 255;
    __syncthreads();
    for (int i = 0; i < 8; ++i) {
        int base = g*16 + i*2;
        {
            int j = base + p_s;
            int jj = j < NPAIR ? j : NPAIR - 1;
            s_x[p_s][kk] = nodes[(jj + (kk < 128 ? 1 : 0))*EMB + (kk & 127)];
        }
        __syncthreads();
        float a0 = 0.f, a1 = 0.f;
        #pragma unroll
        for (int j = 0; j < 64; ++j) {
            float w = wy[j];
            a0 += s_x[0][q4*64 + j] * w;
            a1 += s_x[1][q4*64 + j] * w;
        }
        s_red[q4][0][o] = a0;
        s_red[q4][1][o] = a1;
        __syncthreads();
        if (tid < 256) {
            int p = tid >> 7, oo = tid & 127;
            float yv = s_red[0][p][oo] + s_red[1][p][oo] + s_red[2][p][oo] + s_red[3][p][oo] + s_by[oo];
            s_y[p][oo] = yv;
            int j2 = base + p;
            if (j2 < NPAIR) yc[(size_t)j2*EMB + oo] = yv;
        }
        __syncthreads();
        float c0 = 0.f, c1 = 0.f;
        #pragma unroll
        for (int j = 0; j < 64; ++j) {
            float w = wxx[j];
            c0 += s_y[0][hh*64 + j] * w;
            c1 += s_y[1][hh*64 + j] * w;
        }
        s_redx[hh][0][c] = c0;
        s_redx[hh][1][c] = c1;
        __syncthreads();
        if (tid < 256) {   // waves 0-3: (pair p2, half h2)
            int w = tid >> 6, lane = tid & 63;
            int p2 = w >> 1, h2 = w & 1;
            int cA = h2*128 + lane, cB = cA + 64;
            float v0 = s_redx[0][p2][cA] + s_redx[1][p2][cA] + s_bxx[cA];
            float v1 = s_redx[0][p2][cB] + s_redx[1][p2][cB] + s_bxx[cB];
            float m = fmaxf(v0, v1);
            for (int s = 32; s; s >>= 1) m = fmaxf(m, __shfl_xor(m, s, 64));
            float se = expf(v0 - m) + expf(v1 - m);
            for (int s = 32; s; s >>= 1) se += __shfl_xor(se, s, 64);
            float lse = m + logf(se);
            float o0 = s_x[p2][cA], o1 = s_x[p2][cB];
            float term = o0*(v0 - lse) + o1*(v1 - lse);
            for (int s = 32; s; s >>= 1) term += __shfl_xor(term, s, 64);
            if (lane == 0) s_ls[p2][h2] = -term;
        }
        __syncthreads();
        if (tid < 2) {
            int j2 = base + tid;
            if (j2 < NPAIR) {
                float l = ((1.f+EPSF)*s_ls[tid][0] + (1.f+EPSF)*s_ls[tid][1]) / (2.f + EPSF);
                ws[OFF_L0 + b*NPAIR + j2] = l;
            }
        }
        __syncthreads();
    }
}

// padded staged-x access: 64-chunk stride 72 floats
#define SX(p, c) s_x[p][(((c) >> 6)*72) + ((c) & 63)]

// ---------------- sequential scan: one block (512 thr) per batch row --------
// Session-best configuration (R16: k_seq 380us, total 492us, absmax 0):
// interleaved coalesced weight layout (fixes the silent 64-way-uncoalesced
// compiler re-stream), b128 LDS reads, DPP reductions, 4 barriers/step:
// S1 | S2 | softmax||argmin | S4.
__global__ void __launch_bounds__(512, 1) k_seq(float* __restrict__ ws,
                      const float* __restrict__ Wk, const float* __restrict__ bkv,
                      float* __restrict__ out) {
    __shared__ float s_nodes[SEQ*EMB];    // 64 KB
    __shared__ float s_yc[NPAIR*EMB];     // 63.5 KB
    __shared__ float s_x[2][4*72];        // padded chunks
    __shared__ float s_y[2][EMB];
    __shared__ float s_xx[2][2*EMB];
    __shared__ float s_by[EMB];
    __shared__ float s_bxx[2*EMB];
    __shared__ float s_ls[2][2];
    __shared__ float s_loss[2][SEQ];      // ping-pong
    __shared__ float s_cnt[2][SEQ];
    __shared__ int   s_nslot[2][SEQ];
    __shared__ int   s_yslot[2][SEQ];
    __shared__ float s_restv[4];
    __shared__ int   s_resti[4];
    __shared__ float s_log[KCLS];

    int tid = threadIdx.x;
    int b = blockIdx.x;
    const float4* gwy  = (const float4*)(ws + OFF_WYT);   // slice == tid
    const float4* gwxx = (const float4*)(ws + OFF_WXXT);  // slice == tid
    float wy[64], wxx[64];
    {
        #pragma unroll
        for (int i = 0; i < 16; ++i) { float4 v = gwy[i*512 + tid]; wy[4*i]=v.x; wy[4*i+1]=v.y; wy[4*i+2]=v.z; wy[4*i+3]=v.w; }
        #pragma unroll
        for (int i = 0; i < 16; ++i) { float4 v = gwxx[i*512 + tid]; wxx[4*i]=v.x; wxx[4*i+1]=v.y; wxx[4*i+2]=v.z; wxx[4*i+3]=v.w; }
    }
    {
        const float4* gn = (const float4*)(ws + OFF_NODES + (size_t)b*SEQ*EMB);
        float4* sn = (float4*)s_nodes;
        for (int i = tid; i < SEQ*EMB/4; i += 512) sn[i] = gn[i];
        const float4* gy = (const float4*)(ws + OFF_YC + (size_t)b*NPAIR*EMB);
        float4* sy = (float4*)s_yc;
        for (int i = tid; i < NPAIR*EMB/4; i += 512) sy[i] = gy[i];
    }
    if (tid < EMB) s_by[tid] = ws[OFF_BY + tid];
    if (tid < 2*EMB) s_bxx[tid] = ws[OFF_BXX + tid];
    if (tid < NPAIR) { s_loss[0][tid] = ws[OFF_L0 + b*NPAIR + tid]; s_yslot[0][tid] = tid; }
    if (tid < SEQ)   { s_cnt[0][tid] = 1.f; s_nslot[0][tid] = tid; }

    float acc = 0.f;
    int cur = 0;
    int q0c = -1, q1c = -1;               // current-step recompute positions (uniform regs)
    const int q4 = tid & 3,  oy = tid >> 2;   // S1 roles: k-chunk in lane&3
    const int hh = tid & 1,  cx = tid >> 1;   // S2 roles: k-half in lane&1
    const int sp = tid >> 8, skk = tid & 255; // stage roles
    __syncthreads();

    #pragma unroll 1
    for (int t = 0; t < NPAIR; ++t) {
        const int L = SEQ - t;
        if (t > 0) {
            // ---- S1: y = x @ Wy + by; x via ds_read_b128; DPP-reduce 4 chunks
            {
                const float4* x0q = (const float4*)(&s_x[0][q4*72]);
                const float4* x1q = (const float4*)(&s_x[1][q4*72]);
                float a0 = 0.f, a1 = 0.f;
                #pragma unroll
                for (int i = 0; i < 16; ++i) {
                    float4 u0 = x0q[i];
                    float4 u1 = x1q[i];
                    a0 = fmaf(u0.x, wy[4*i],   a0); a1 = fmaf(u1.x, wy[4*i],   a1);
                    a0 = fmaf(u0.y, wy[4*i+1], a0); a1 = fmaf(u1.y, wy[4*i+1], a1);
                    a0 = fmaf(u0.z, wy[4*i+2], a0); a1 = fmaf(u1.z, wy[4*i+2], a1);
                    a0 = fmaf(u0.w, wy[4*i+3], a0); a1 = fmaf(u1.w, wy[4*i+3], a1);
                }
                a0 += DPPF(a0, 0xB1); a1 += DPPF(a1, 0xB1);
                a0 += DPPF(a0, 0x4E); a1 += DPPF(a1, 0x4E);
                if (q4 == 0) {
                    float bb = s_by[oy];
                    float y0 = a0 + bb, y1 = a1 + bb;
                    s_y[0][oy] = y0; s_y[1][oy] = y1;
                    s_yc[(size_t)s_yslot[cur][q0c]*EMB + oy] = y0;
                    s_yc[(size_t)s_yslot[cur][q1c]*EMB + oy] = y1;
                }
            }
            __syncthreads();
            // ---- S2: xx = y @ Wxx + bxx; y via ds_read_b128; DPP-reduce 2 halves
            {
                const float4* y0q = (const float4*)(&s_y[0][hh*64]);
                const float4* y1q = (const float4*)(&s_y[1][hh*64]);
                float c0 = 0.f, c1 = 0.f;
                #pragma unroll
                for (int i = 0; i < 16; ++i) {
                    float4 u0 = y0q[i];
                    float4 u1 = y1q[i];
                    c0 = fmaf(u0.x, wxx[4*i],   c0); c1 = fmaf(u1.x, wxx[4*i],   c1);
                    c0 = fmaf(u0.y, wxx[4*i+1], c0); c1 = fmaf(u1.y, wxx[4*i+1], c1);
                    c0 = fmaf(u0.z, wxx[4*i+2], c0); c1 = fmaf(u1.z, wxx[4*i+2], c1);
                    c0 = fmaf(u0.w, wxx[4*i+3], c0); c1 = fmaf(u1.w, wxx[4*i+3], c1);
                }
                c0 += DPPF(c0, 0xB1); c1 += DPPF(c1, 0xB1);
                if (hh == 0) {
                    float bb = s_bxx[cx];
                    s_xx[0][cx] = c0 + bb;
                    s_xx[1][cx] = c1 + bb;
                }
            }
            __syncthreads();
        }
        // ---- S3: softmax losses (waves 0-1, DPP trees) || argmin (waves 2-3)
        if (t > 0 && tid < 128) {
            int p2 = tid >> 6, h2 = (tid >> 5) & 1, l5 = tid & 31;
            int base = h2*128 + l5;
            float v0 = s_xx[p2][base],      v1 = s_xx[p2][base+32];
            float v2 = s_xx[p2][base+64],   v3 = s_xx[p2][base+96];
            float o0 = SX(p2, base),        o1v = SX(p2, base+32);
            float o2 = SX(p2, base+64),     o3 = SX(p2, base+96);
            float m   = fmaxf(fmaxf(v0, v1), fmaxf(v2, v3));
            float sov = v0*o0 + v1*o1v + v2*o2 + v3*o3;
            float so  = (o0 + o1v) + (o2 + o3);
            m = fmaxf(m, DPPF(m, 0xB1));  sov += DPPF(sov, 0xB1);  so += DPPF(so, 0xB1);
            m = fmaxf(m, DPPF(m, 0x4E));  sov += DPPF(sov, 0x4E);  so += DPPF(so, 0x4E);
            m = fmaxf(m, DPPF(m, 0x124)); sov += DPPF(sov, 0x124); so += DPPF(so, 0x124);
            m = fmaxf(m, DPPF(m, 0x128)); sov += DPPF(sov, 0x128); so += DPPF(so, 0x128);
            m = fmaxf(m, SWZ16F(m));      sov += SWZ16F(sov);      so += SWZ16F(so);
            float se = expf(v0 - m) + expf(v1 - m) + expf(v2 - m) + expf(v3 - m);
            se += DPPF(se, 0xB1);
            se += DPPF(se, 0x4E);
            se += DPPF(se, 0x124);
            se += DPPF(se, 0x128);
            se += SWZ16F(se);
            if (l5 == 0) s_ls[p2][h2] = (m + logf(se))*so - sov;   // = -sum o*(v-lse)
        } else if (tid >= 128 && tid < 256) {
            int j = tid - 128;
            float v = (j <= L-2 && j != q0c && j != q1c) ? s_loss[cur][j] : INFINITY;
            int ii = j;
            {   float ov = DPPF(v, 0xB1);  int oi = DPPI(ii, 0xB1);
                bool tk = (ov < v) || (ov == v && oi < ii); v = tk ? ov : v; ii = tk ? oi : ii; }
            {   float ov = DPPF(v, 0x4E);  int oi = DPPI(ii, 0x4E);
                bool tk = (ov < v) || (ov == v && oi < ii); v = tk ? ov : v; ii = tk ? oi : ii; }
            {   float ov = DPPF(v, 0x124); int oi = DPPI(ii, 0x124);
                bool tk = (ov < v) || (ov == v && oi < ii); v = tk ? ov : v; ii = tk ? oi : ii; }
            {   float ov = DPPF(v, 0x128); int oi = DPPI(ii, 0x128);
                bool tk = (ov < v) || (ov == v && oi < ii); v = tk ? ov : v; ii = tk ? oi : ii; }
            {   float ov = SWZ16F(v);      int oi = SWZ16I(ii);
                bool tk = (ov < v) || (ov == v && oi < ii); v = tk ? ov : v; ii = tk ? oi : ii; }
            if ((j & 31) == 0) { s_restv[j >> 5] = v; s_resti[j >> 5] = ii; }
        }
        __syncthreads();
        // ---- S4: uniform combine + ping-pong shift + father write + stage
        float l0 = INFINITY, l1 = INFINITY;
        if (t > 0) {
            float n1a = s_cnt[cur][q0c+1], n2a = s_cnt[cur][q0c];
            l0 = ((n1a + EPSF)*s_ls[0][0] + (n2a + EPSF)*s_ls[0][1]) / (n1a + n2a + EPSF);
            float n1b = s_cnt[cur][q1c+1], n2b = s_cnt[cur][q1c];
            l1 = ((n1b + EPSF)*s_ls[1][0] + (n2b + EPSF)*s_ls[1][1]) / (n1b + n2b + EPSF);
        }
        float bv = s_restv[0]; int bi = s_resti[0];
        #pragma unroll
        for (int g = 1; g < 4; ++g) {
            float rv = s_restv[g]; int ri = s_resti[g];
            if (rv < bv || (rv == bv && ri < bi)) { bv = rv; bi = ri; }
        }
        if (t > 0) {   // q1 first then q0, so q0 wins ties (first-index rule)
            if (l1 < bv || (l1 == bv && q1c < bi)) { bv = l1; bi = q1c; }
            if (l0 < bv || (l0 == bv && q0c < bi)) { bv = l0; bi = q0c; }
        }
        if (tid == 0) acc += bv;
        const int idx = bi;
        const int pos = idx > 0 ? idx - 1 : 0;
        const bool dS = idx > 0;
        const float fcnt = s_cnt[cur][idx] + s_cnt[cur][idx == 0 ? L-1 : idx-1];
        const int slotFr = s_nslot[cur][pos];
        const int ysIr   = s_yslot[cur][idx];
        const int nxt = cur ^ 1;
        if (tid < NPAIR) {
            int sh = (dS && tid >= pos+1 && tid <= L-3) ? 1 : 0;
            int sj = tid + sh;
            float v = (sj == q0c) ? l0 : (sj == q1c) ? l1 : s_loss[cur][sj];
            s_loss[nxt][tid]  = v;
            s_yslot[nxt][tid] = s_yslot[cur][sj];
        }
        if (tid < SEQ) {
            int sh = (dS && tid >= pos+1 && tid <= L-2) ? 1 : 0;
            s_cnt[nxt][tid]   = (tid == pos) ? fcnt : s_cnt[cur][tid + sh];
            s_nslot[nxt][tid] = s_nslot[cur][tid + sh];
        }
        // next-step roles (uniform)
        q0c = pos >= 1 ? pos - 1 : 0;
        q1c = pos;
        // father write + next-step x staging (race-free: stage's father
        // position redirects to s_yc; other slots differ from slotFr)
        if (tid < EMB) s_nodes[slotFr*EMB + tid] = s_yc[(size_t)ysIr*EMB + tid];
        {
            int qq = (sp ? q1c : q0c) + (skk < 128 ? 1 : 0);
            bool sYc = (qq == q1c);   // father position reads fresh y from yc
            int sh = (dS && qq >= pos+1 && qq <= L-2) ? 1 : 0;
            int ms = s_nslot[cur][qq + sh];
            float xv = sYc ? s_yc[(size_t)ysIr*EMB + (skk & 127)]
                           : s_nodes[(size_t)ms*EMB + (skk & 127)];
            s_x[sp][((skk >> 6)*72) + (skk & 63)] = xv;
        }
        cur = nxt;
        __syncthreads();
    }
    // ---- prediction from root = s_nodes[s_nslot[cur][0]]
    {
        int w = tid >> 6, l = tid & 63;
        if (w < KCLS) {
            const float* root = s_nodes + (size_t)s_nslot[cur][0]*EMB;
            float p = root[2*l]*Wk[(2*l)*KCLS + w] + root[2*l+1]*Wk[(2*l+1)*KCLS + w];
            for (int s = 32; s; s >>= 1) p += __shfl_xor(p, s, 64);
            if (l == 0) s_log[w] = p + bkv[w];
        }
    }
    __syncthreads();
    if (tid == 0) {
        int best = 0;
        for (int cc = 1; cc < KCLS; ++cc) if (s_log[cc] > s_log[best]) best = cc;
        out[b] = (float)best;
        atomicAdd(&out[BATCH], acc * (1.f/16.f));
    }
}

extern "C" void kernel_launch(void* const* d_in, const int* in_sizes, int n_in,
                              void* d_out, int out_size, void* d_ws, size_t ws_size,
                              hipStream_t stream) {
    const int*   inp = (const int*)d_in[0];
    const float* emb = (const float*)d_in[1];
    const float* W1  = (const float*)d_in[2];
    const float* b1  = (const float*)d_in[3];
    const float* W2  = (const float*)d_in[4];
    const float* b2  = (const float*)d_in[5];
    const float* W3  = (const float*)d_in[6];
    const float* b3  = (const float*)d_in[7];
    const float* W4  = (const float*)d_in[8];
    const float* b4  = (const float*)d_in[9];
    const float* Wk  = (const float*)d_in[10];
    const float* bk  = (const float*)d_in[11];
    float* out = (float*)d_out;
    float* ws  = (float*)d_ws;

    hipMemsetAsync(d_out, 0, (size_t)out_size * sizeof(float), stream);

    k_comp<<<(65920 + 255) / 256, 256, 0, stream>>>(W1, b1, W2, b2, W3, b3, W4, b4, ws);
    k_nodes<<<(BATCH*SEQ*EMB + 255) / 256, 256, 0, stream>>>(inp, emb, ws);
    k_init<<<BATCH * 8, 512, 0, stream>>>(ws);
    k_seq<<<BATCH, 512, 0, stream>>>(ws, Wk, bk, out);
}